// Round 1
// baseline (1061.020 us; speedup 1.0000x reference)
//
#include <hip/hip_runtime.h>
#include <math.h>

#define FEAT 128
#define NANG 7      // 1 + 2*MAX_F
#define TPB  256    // threads per block == triplets per block chunk

static constexpr float INV_SQRT_PI = 0.5641895835477563f;
static constexpr float INV_SQRT_2  = 0.7071067811865476f;

// W_c[i][j] = sum_k W_swish[i][k] * W_angle[k][j], scaled by 1/sqrt(pi)
// (and column 0 additionally by 1/sqrt(2), folding the basis const term).
// Stored padded to 8 columns (col 7 = 0).
__global__ void wc_kernel(const float* __restrict__ W_angle,  // [128][7]
                          const float* __restrict__ W_swish,  // [128][128]
                          float* __restrict__ wc)             // [128][8]
{
    int tid = threadIdx.x;                 // 0..895
    if (tid >= FEAT * NANG) return;
    int i = tid & (FEAT - 1);              // feature row 0..127
    int j = tid >> 7;                      // angular col 0..6
    float s = 0.f;
    #pragma unroll 8
    for (int k = 0; k < FEAT; ++k)
        s = fmaf(W_swish[i * FEAT + k], W_angle[k * NANG + j], s);
    s *= INV_SQRT_PI;
    if (j == 0) {
        s *= INV_SQRT_2;
        wc[i * 8 + 7] = 0.f;
    }
    wc[i * 8 + j] = s;
}

__global__ __launch_bounds__(TPB) void triplet_kernel(
    const float* __restrict__ vecs,    // [E][3]
    const int*   __restrict__ tgt,     // [T]
    const int*   __restrict__ src,     // [T]
    const float* __restrict__ freqs,   // [3]
    const float* __restrict__ wc,      // [128][8]
    float*       __restrict__ out,     // [T][128]
    int T)
{
    __shared__ float basis[TPB][8];    // 8 KB
    const int tid = threadIdx.x;
    const int sub = tid & 31;          // output quad within a triplet
    const int grp = tid >> 5;          // 0..7: which triplet of the 8-wide slab
    const long long blockBase = (long long)blockIdx.x * TPB;

    // Per-thread weight rows for phase 2: rows 4*sub .. 4*sub+3 (block-invariant,
    // broadcast loads, L1-resident).
    float4 w0[4], w1[4];
    #pragma unroll
    for (int r = 0; r < 4; ++r) {
        const float* wr = wc + (sub * 4 + r) * 8;
        w0[r] = *(const float4*)(wr);
        w1[r] = *(const float4*)(wr + 4);
    }

    // ---- Phase 1: one triplet's Fourier basis per thread -> LDS ----
    {
        long long t = blockBase + tid;
        float s1 = 0.f, s2 = 0.f, s3 = 0.f, c1 = 0.f, c2 = 0.f, c3 = 0.f;
        if (t < T) {
            int e1 = tgt[t];
            int e2 = src[t];
            const float* v1 = vecs + 3ll * e1;
            const float* v2 = vecs + 3ll * e2;
            float d = v1[0] * v2[0] + v1[1] * v2[1] + v1[2] * v2[2];
            d *= (1.0f - 1e-6f);
            float a = acosf(d);
            float f1 = freqs[0], f2 = freqs[1], f3 = freqs[2];
            sincosf(f1 * a, &s1, &c1);
            sincosf(f2 * a, &s2, &c2);
            sincosf(f3 * a, &s3, &c3);
        }
        basis[tid][0] = 1.f;
        basis[tid][1] = s1; basis[tid][2] = s2; basis[tid][3] = s3;
        basis[tid][4] = c1; basis[tid][5] = c2; basis[tid][6] = c3;
        basis[tid][7] = 0.f;
    }
    __syncthreads();

    // ---- Phase 2: 32-thread groups emit 128 outputs per triplet ----
    for (int tt = 0; tt < TPB; tt += 8) {
        long long t = blockBase + tt + grp;
        // LDS broadcast reads (same address across the 32-lane group)
        float4 b0 = *(const float4*)&basis[tt + grp][0];
        float4 b1 = *(const float4*)&basis[tt + grp][4];
        float4 o;
        #pragma unroll
        for (int r = 0; r < 4; ++r) {
            float h = b0.x * w0[r].x + b0.y * w0[r].y + b0.z * w0[r].z + b0.w * w0[r].w
                    + b1.x * w1[r].x + b1.y * w1[r].y + b1.z * w1[r].z + b1.w * w1[r].w;
            float e  = __expf(-h);
            float sg = __builtin_amdgcn_rcpf(1.0f + e);
            (&o.x)[r] = h * sg;
        }
        if (t < T) {
            *(float4*)(out + (size_t)t * FEAT + sub * 4) = o;
        }
    }
}

extern "C" void kernel_launch(void* const* d_in, const int* in_sizes, int n_in,
                              void* d_out, int out_size, void* d_ws, size_t ws_size,
                              hipStream_t stream) {
    const float* vecs  = (const float*)d_in[0];
    const int*   tgt   = (const int*)  d_in[1];
    const int*   src   = (const int*)  d_in[2];
    const float* freqs = (const float*)d_in[3];
    const float* Wa    = (const float*)d_in[4];
    const float* Ws    = (const float*)d_in[5];
    float* out = (float*)d_out;
    float* wc  = (float*)d_ws;     // 128*8 floats = 4 KB scratch

    const int T = in_sizes[1];

    wc_kernel<<<1, FEAT * NANG, 0, stream>>>(Wa, Ws, wc);

    const int nblocks = (T + TPB - 1) / TPB;
    triplet_kernel<<<nblocks, TPB, 0, stream>>>(vecs, tgt, src, freqs, wc, out, T);
}